// Round 1
// baseline (1051.702 us; speedup 1.0000x reference)
//
#include <hip/hip_runtime.h>

// talinear: out[b,g,i,j] = leaky( sum_{e,t} inp[b,g,e,t] * 0.5*(ww+dw)[t,e,i,j] + 0.5*(wb+db) )
// B=64 G=307 E=64 T=12 -> per-sample GEMM M=307 N=768 K=768 (k = e*12+t, n = i*12+j)
//
// Kernel 1 (prep): gather+average weights -> bf16, transposed to WcT[b][n][k] (K-contiguous
//                  for MFMA B-frags); also convert inputs fp32 -> bf16 A[b][g][k] (layout free).
// Kernel 2 (gemm): 128x128 tile, BK=32, 4 waves (2x2), mfma_f32_16x16x32_bf16 4x4 acc/wave,
//                  global_load_lds width=16 staging, fused fp32 bias + LeakyReLU epilogue.

#define G_DIM 307
#define KDIM  768          // E*T (contraction), also N = E*T (output i*T+j)
#define TEB   589824       // T*E*E*T elements per weight state
#define BIAS_STRIDE 235776 // G*E*T
#define WBLOCKS 9216       // 64 samples * 12 * 12 (64x64 tiles of the 768x768 transpose)
#define ABLOCKS 14736      // 3772416 float4 / 256
#define A_N4   3772416
#define WCT_BYTES 75497472ull // 64*768*768*2

typedef __bf16 bf16x8 __attribute__((ext_vector_type(8)));
typedef float  f32x4  __attribute__((ext_vector_type(4)));

struct __align__(16) i4v { int x, y, z, w; };
struct __align__(8)  i2v { int x, y; };

__device__ __forceinline__ unsigned short f2bf(float f) {
  union { float f; unsigned int u; } a; a.f = f;
  unsigned int r = a.u + 0x7fffu + ((a.u >> 16) & 1u);  // RNE
  return (unsigned short)(r >> 16);
}

__device__ __forceinline__ void load_lds16(const void* g, void* l) {
  __builtin_amdgcn_global_load_lds(
      (const __attribute__((address_space(1))) unsigned int*)g,
      (__attribute__((address_space(3))) unsigned int*)l, 16, 0, 0);
}

// ---------------- Kernel 1: weight combine + transpose, and A fp32->bf16 ----------------
__global__ __launch_bounds__(256) void prep_kernel(
    const float* __restrict__ wws, const float* __restrict__ dws,
    const int* __restrict__ week, const int* __restrict__ date,
    unsigned short* __restrict__ WcT,
    const float* __restrict__ inputs, unsigned short* __restrict__ Abf)
{
  int bid = blockIdx.x;
  int tid = threadIdx.x;
  if (bid < WBLOCKS) {
    // One 64(k) x 64(n) tile of the per-sample transpose:
    //   WcT[b][n][k=e*12+t] = 0.5*(ww[wk] + dw[dt])[src=(t*64+e)*768 + n]
    __shared__ unsigned short tile[64][68];  // pad 68 for 8B-aligned rows
    int b   = bid / 144;
    int rem = bid - b * 144;
    int kt  = rem / 12;
    int nt  = rem - kt * 12;
    const float4* wwb = (const float4*)(wws + (size_t)week[b] * TEB);
    const float4* dwb = (const float4*)(dws + (size_t)date[b] * TEB);
    int f4 = tid & 15;   // float4 index along n
    int kb = tid >> 4;   // 0..15
    int k0 = kt * 64, n0 = nt * 64;
    #pragma unroll
    for (int it = 0; it < 4; ++it) {
      int kk = it * 16 + kb;
      int k  = k0 + kk;
      int e  = k / 12;
      int t  = k - e * 12;
      int src = (t * 64 + e) * 192 + nt * 16 + f4;  // float4 index; row reads coalesced
      float4 w = wwb[src];
      float4 d = dwb[src];
      int nn = f4 * 4;
      tile[kk][nn + 0] = f2bf(0.5f * (w.x + d.x));
      tile[kk][nn + 1] = f2bf(0.5f * (w.y + d.y));
      tile[kk][nn + 2] = f2bf(0.5f * (w.z + d.z));
      tile[kk][nn + 3] = f2bf(0.5f * (w.w + d.w));
    }
    __syncthreads();
    // write transposed: rows n, 8 bf16 (16B) per thread, fully coalesced
    int kg = tid & 7;    // k-group of 8
    int nb = tid >> 3;   // 0..31
    #pragma unroll
    for (int it = 0; it < 2; ++it) {
      int nn = nb + it * 32;
      union { unsigned short h[8]; i4v v; } u;
      #pragma unroll
      for (int j = 0; j < 8; ++j) u.h[j] = tile[kg * 8 + j][nn];
      size_t dst = ((size_t)b * 768 + n0 + nn) * 768 + k0 + kg * 8;
      *(i4v*)(WcT + dst) = u.v;
    }
  } else {
    // A convert: inputs[b,g,e,t] is already [g][k=e*12+t] contiguous -> pure elementwise
    int i = (bid - WBLOCKS) * 256 + tid;
    if (i < A_N4) {
      float4 f = ((const float4*)inputs)[i];
      union { unsigned short h[4]; i2v v; } u;
      u.h[0] = f2bf(f.x); u.h[1] = f2bf(f.y);
      u.h[2] = f2bf(f.z); u.h[3] = f2bf(f.w);
      ((i2v*)Abf)[i] = u.v;
    }
  }
}

// ---------------- Kernel 2: per-sample bf16 GEMM-BT + bias + LeakyReLU ----------------
// grid = 64 samples * 3 m-tiles * 6 n-tiles = 1152 blocks, 256 threads (4 waves, 2x2)
__global__ __launch_bounds__(256) void gemm_kernel(
    const unsigned short* __restrict__ Abf, const unsigned short* __restrict__ WcT,
    const int* __restrict__ week, const int* __restrict__ date,
    const float* __restrict__ wbias, const float* __restrict__ dbias,
    float* __restrict__ out)
{
  __shared__ __align__(16) unsigned short As[128 * 32];  // 8 KB, rows g-local, 64B/row
  __shared__ __align__(16) unsigned short Bs[128 * 32];  // 8 KB, rows n-local (B^T layout)
  int bid = blockIdx.x;
  int b     = bid / 18;
  int rem   = bid - b * 18;
  int mt    = rem / 6;
  int ntile = rem - mt * 6;
  int g0 = mt * 128, n0 = ntile * 128;
  int tid  = threadIdx.x;
  int wave = tid >> 6, lane = tid & 63;
  int wm = wave & 1, wn = wave >> 1;
  const unsigned short* Ab = Abf + (size_t)b * G_DIM * 768;
  const unsigned short* Bb = WcT + (size_t)b * 768 * 768;

  f32x4 zero = {0.f, 0.f, 0.f, 0.f};
  f32x4 acc[4][4];
  #pragma unroll
  for (int i = 0; i < 4; ++i)
    #pragma unroll
    for (int j = 0; j < 4; ++j) acc[i][j] = zero;

  // staging geometry: lds byte o = issue*4096 + wave*1024 + lane*16 (wave-uniform base + lane*16)
  int o0 = wave * 1024 + lane * 16;
  int o1 = o0 + 4096;
  int rowA0 = o0 >> 6, colA0 = o0 & 63;
  int rowA1 = o1 >> 6, colA1 = o1 & 63;
  int gA0 = g0 + rowA0; if (gA0 > G_DIM - 1) gA0 = G_DIM - 1;  // clamp: read valid, discard later
  int gA1 = g0 + rowA1; if (gA1 > G_DIM - 1) gA1 = G_DIM - 1;
  const char* aSrc0 = (const char*)(Ab + (size_t)gA0 * 768) + colA0;
  const char* aSrc1 = (const char*)(Ab + (size_t)gA1 * 768) + colA1;
  const char* bSrc0 = (const char*)(Bb + (size_t)(n0 + rowA0) * 768) + colA0;
  const char* bSrc1 = (const char*)(Bb + (size_t)(n0 + rowA1) * 768) + colA1;
  char* aDst0 = (char*)As + o0;  char* aDst1 = (char*)As + o1;
  char* bDst0 = (char*)Bs + o0;  char* bDst1 = (char*)Bs + o1;

  int r = lane & 15, q = lane >> 4;
  int aoff = (wm * 64 + r) * 64 + q * 16;  // +i*1024 per 16-row step
  int boff = (wn * 64 + r) * 64 + q * 16;

  for (int ks = 0; ks < 24; ++ks) {
    __syncthreads();                       // protect LDS from overwrite
    load_lds16(aSrc0, aDst0);
    load_lds16(aSrc1, aDst1);
    load_lds16(bSrc0, bDst0);
    load_lds16(bSrc1, bDst1);
    aSrc0 += 64; aSrc1 += 64; bSrc0 += 64; bSrc1 += 64;  // k0 += 32 elems
    __builtin_amdgcn_s_waitcnt(0);         // ensure global->LDS complete before barrier
    __syncthreads();
    bf16x8 af[4], bfr[4];
    #pragma unroll
    for (int i = 0; i < 4; ++i) {
      af[i]  = *(const bf16x8*)((const char*)As + aoff + i * 1024);  // A[m][k=q*8+j]
      bfr[i] = *(const bf16x8*)((const char*)Bs + boff + i * 1024);  // B[k=q*8+j][n]
    }
    #pragma unroll
    for (int i = 0; i < 4; ++i)
      #pragma unroll
      for (int j = 0; j < 4; ++j)
        acc[i][j] = __builtin_amdgcn_mfma_f32_16x16x32_bf16(af[i], bfr[j], acc[i][j], 0, 0, 0);
  }

  // epilogue: C/D layout col=lane&15, row=(lane>>4)*4+reg
  const float* wbb = wbias + (size_t)week[b] * BIAS_STRIDE;
  const float* dbb = dbias + (size_t)date[b] * BIAS_STRIDE;
  float* outb = out + (size_t)b * BIAS_STRIDE;
  #pragma unroll
  for (int i = 0; i < 4; ++i) {
    int gb = g0 + wm * 64 + i * 16 + q * 4;
    #pragma unroll
    for (int j = 0; j < 4; ++j) {
      int n = n0 + wn * 64 + j * 16 + r;
      #pragma unroll
      for (int rr = 0; rr < 4; ++rr) {
        int g = gb + rr;
        if (g < G_DIM) {
          size_t idx = (size_t)g * 768 + n;
          float v = acc[i][j][rr] + 0.5f * (wbb[idx] + dbb[idx]);
          outb[idx] = v > 0.f ? v : 0.3f * v;
        }
      }
    }
  }
}

extern "C" void kernel_launch(void* const* d_in, const int* in_sizes, int n_in,
                              void* d_out, int out_size, void* d_ws, size_t ws_size,
                              hipStream_t stream) {
  const float* inputs = (const float*)d_in[0];
  const int*   week   = (const int*)d_in[1];
  const int*   date   = (const int*)d_in[2];
  const float* wws    = (const float*)d_in[3];
  const float* wbs    = (const float*)d_in[4];
  const float* dws    = (const float*)d_in[5];
  const float* dbs    = (const float*)d_in[6];
  float* out = (float*)d_out;

  unsigned short* WcT = (unsigned short*)d_ws;                       // 75,497,472 B
  unsigned short* Abf = (unsigned short*)((char*)d_ws + WCT_BYTES);  // 30,179,328 B

  prep_kernel<<<WBLOCKS + ABLOCKS, 256, 0, stream>>>(wws, dws, week, date, WcT, inputs, Abf);
  gemm_kernel<<<64 * 3 * 6, 256, 0, stream>>>(Abf, WcT, week, date, wbs, dbs, out);
}